// Round 4
// baseline (428.425 us; speedup 1.0000x reference)
//
#include <hip/hip_runtime.h>
#include <math.h>

// Problem constants (fixed by the reference)
#define MM 12       // M
#define KK 2        // K
#define DD 512      // D
#define CIN 4096    // C_IN
#define NCLS 8
#define NV 16       // N (videos) == LSTM step count
#define TT 32       // T
// Only LSTM batch row t=31 is ever consumed (rows independent; out uses hs[:, -1, :]).

typedef unsigned long long u64;

// ws layout (floats) — small buffers first, split-K partials last so the
// partial count can adapt to ws_size at runtime.
#define POOLED_F 0                    // 16*512
#define GX_F     8192                 // 16*2048
#define SLOT_F   40960                // 16*512 u64 = 16384 floats
#define PART_F   57344                // KS * 192 * 1024 floats
#define PART_STRIDE (192 * 1024)

// ---------------------------------------------------------------------------
// Kernel 1: split-K GEMM  part[ks][j][o] = sum_{cc in chunk} w_a[o,cc]*B[j,cc]
// Tile: 64(o) x 192(all j), micro 4x12, KS-way split-K, 16cc stages, prefetch.
// KS=16 -> grid 256 WGs (1/CU). LDS per FMA: 64B/48FMA = 1.33 (vs 2.0 at 4x4).
// ---------------------------------------------------------------------------
template <int KS>
__global__ __launch_bounds__(256) void k_gemm(const float* __restrict__ w_a,
                                              const float* __restrict__ base_out,
                                              float* __restrict__ part) {
    const int ks = blockIdx.x;   // 0..KS-1
    const int ot = blockIdx.y;   // 0..15
    const int tid = threadIdx.x;
    constexpr int CHUNK = CIN / KS;
    constexpr int ITS = CHUNK / 16;

    __shared__ __align__(16) float As[16][68];
    __shared__ __align__(16) float Bs[16][196];

    const int to = tid & 15;     // o micro (4 consecutive o)
    const int tj = tid >> 4;     // j micro (12 consecutive j)

    // staging roles
    const int arow = tid >> 2;   // 0..63
    const int aq   = tid & 3;    // cc float4 quad
    const size_t a_base = (size_t)(ot * 64 + arow) * CIN;

    size_t b_base[3];
#pragma unroll
    for (int rep = 0; rep < 3; ++rep) {
        const int j = arow + 64 * rep;           // 0..191
        const int n = j / 12, m = j - n * 12;
        b_base[rep] = (size_t)((n * TT + 31) * MM + m) * CIN;
    }

    float acc[4][12];
#pragma unroll
    for (int i = 0; i < 4; ++i)
#pragma unroll
        for (int jj = 0; jj < 12; ++jj) acc[i][jj] = 0.f;

    int cc0 = ks * CHUNK;
    float4 av = *(const float4*)&w_a[a_base + cc0 + aq * 4];
    float4 bv[3];
#pragma unroll
    for (int rep = 0; rep < 3; ++rep)
        bv[rep] = *(const float4*)&base_out[b_base[rep] + cc0 + aq * 4];

    for (int it = 0; it < ITS; ++it) {
        __syncthreads();
        As[aq * 4 + 0][arow] = av.x; As[aq * 4 + 1][arow] = av.y;
        As[aq * 4 + 2][arow] = av.z; As[aq * 4 + 3][arow] = av.w;
#pragma unroll
        for (int rep = 0; rep < 3; ++rep) {
            const int br = arow + 64 * rep;
            Bs[aq * 4 + 0][br] = bv[rep].x; Bs[aq * 4 + 1][br] = bv[rep].y;
            Bs[aq * 4 + 2][br] = bv[rep].z; Bs[aq * 4 + 3][br] = bv[rep].w;
        }
        __syncthreads();
        if (it < ITS - 1) {      // prefetch next stage under compute
            cc0 += 16;
            av = *(const float4*)&w_a[a_base + cc0 + aq * 4];
#pragma unroll
            for (int rep = 0; rep < 3; ++rep)
                bv[rep] = *(const float4*)&base_out[b_base[rep] + cc0 + aq * 4];
        }
#pragma unroll
        for (int cl = 0; cl < 16; ++cl) {
            float4 a  = *(const float4*)&As[cl][to * 4];
            float4 b0 = *(const float4*)&Bs[cl][tj * 12 + 0];
            float4 b1 = *(const float4*)&Bs[cl][tj * 12 + 4];
            float4 b2 = *(const float4*)&Bs[cl][tj * 12 + 8];
            const float bb[12] = {b0.x,b0.y,b0.z,b0.w, b1.x,b1.y,b1.z,b1.w,
                                  b2.x,b2.y,b2.z,b2.w};
#pragma unroll
            for (int jj = 0; jj < 12; ++jj) {
                acc[0][jj] += a.x * bb[jj];
                acc[1][jj] += a.y * bb[jj];
                acc[2][jj] += a.z * bb[jj];
                acc[3][jj] += a.w * bb[jj];
            }
        }
    }

    const int o_base = ot * 64 + to * 4;
#pragma unroll
    for (int jj = 0; jj < 12; ++jj) {
        const int j = tj * 12 + jj;
        float4 v = make_float4(acc[0][jj], acc[1][jj], acc[2][jj], acc[3][jj]);
        *(float4*)&part[(size_t)ks * PART_STRIDE + (size_t)j * 1024 + o_base] = v;
    }
}

// ---------------------------------------------------------------------------
// Kernel 2: reduce KS split-K partials, contract with A=sum_p dist, relu,
//           mean over w -> pooled[n, c].  One WG per n.
// ---------------------------------------------------------------------------
__global__ __launch_bounds__(256) void k_pool(const float* __restrict__ part,
                                              const float* __restrict__ dist,
                                              float* __restrict__ pooled, int KS) {
    const int n = blockIdx.x;
    const int tid = threadIdx.x;
    __shared__ float Asum[KK][MM][MM];

    const size_t dbase = (size_t)(n * TT + 31) * (3 * KK * MM * MM);
    for (int f = tid; f < KK * MM * MM; f += 256) {
        const int k = f / (MM * MM);
        const int rem = f - k * (MM * MM);
        float s = dist[dbase + 0 * (KK * MM * MM) + k * (MM * MM) + rem]
                + dist[dbase + 1 * (KK * MM * MM) + k * (MM * MM) + rem]
                + dist[dbase + 2 * (KK * MM * MM) + k * (MM * MM) + rem];
        Asum[k][rem / MM][rem % MM] = s;
    }
    __syncthreads();

    for (int c = tid; c < DD; c += 256) {
        float nd[KK][MM];
#pragma unroll
        for (int k = 0; k < KK; ++k)
#pragma unroll
            for (int v = 0; v < MM; ++v) {
                const size_t off = (size_t)(n * MM + v) * 1024 + (k * DD + c);
                float s = 0.f;
                for (int ks = 0; ks < KS; ++ks)
                    s += part[off + (size_t)ks * PART_STRIDE];
                nd[k][v] = s;
            }
        float accm = 0.f;
#pragma unroll
        for (int w = 0; w < MM; ++w) {
            float sw = 0.f;
#pragma unroll
            for (int k = 0; k < KK; ++k)
#pragma unroll
                for (int v = 0; v < MM; ++v) sw += nd[k][v] * Asum[k][v][w];
            accm += fmaxf(sw, 0.f);
        }
        pooled[n * DD + c] = accm * (1.f / 12.f);
    }
}

// ---------------------------------------------------------------------------
// Kernel 3: gx[n, r] = pooled[n,:] . w_ih[r,:] + b_ih[r] + b_hh[r]
// 128 WGs; WG wg caches w_ih rows [16wg,16wg+16) in LDS (read once device-wide).
// ---------------------------------------------------------------------------
__global__ __launch_bounds__(256) void k_gx(const float* __restrict__ pooled,
                                            const float* __restrict__ w_ih,
                                            const float* __restrict__ b_ih,
                                            const float* __restrict__ b_hh,
                                            float* __restrict__ gx) {
    const int wg = blockIdx.x;   // 0..127
    const int tid = threadIdx.x;
    __shared__ __align__(16) float w_s[16][516];

    for (int f = tid; f < 16 * DD; f += 256) {
        const int r = f >> 9, col = f & 511;
        w_s[r][col] = w_ih[(size_t)(wg * 16 + r) * DD + col];
    }
    __syncthreads();

    const int r = tid & 15;
    const int n = tid >> 4;
    const float4* wr = (const float4*)&w_s[r][0];
    const float4* pv = (const float4*)(pooled + n * DD);
    float acc = 0.f;
#pragma unroll 8
    for (int q = 0; q < DD / 4; ++q) {
        float4 a = wr[q], b = pv[q];
        acc += a.x * b.x + a.y * b.y + a.z * b.z + a.w * b.w;
    }
    const int row = wg * 16 + r;
    gx[n * (4 * DD) + row] = acc + b_ih[row] + b_hh[row];
}

// ---------------------------------------------------------------------------
// Kernel 4: LSTM via tagged dataflow. 128 WGs x 512 threads; WG wg owns h-dims
// [4wg, 4wg+4) (16 w_hh rows = 33 KB LDS). Each thread polls EXACTLY ONE slot
// per step (one observation round). Publish = relaxed agent u64 {h, tag=s+1}.
// ---------------------------------------------------------------------------
__global__ __launch_bounds__(512) void k_lstm(const float* __restrict__ w_hh,
                                              const float* __restrict__ gx,
                                              const float* __restrict__ w_cls,
                                              const float* __restrict__ b_cls,
                                              u64* __restrict__ slots,   // 16*512
                                              float* __restrict__ out) {
    const int wg = blockIdx.x;   // 0..127
    const int tid = threadIdx.x; // 0..511

    __shared__ __align__(16) float whh_s[16][516];
    __shared__ __align__(16) float h_s[DD];
    __shared__ float dot_s[16];

    // preload: row_local rl = gate*4 + dl -> w_hh[gate*512 + wg*4 + dl]
    for (int f = tid; f < 16 * DD; f += 512) {
        const int rl = f >> 9, col = f & 511;
        const int gate = rl >> 2, dl = rl & 3;
        whh_s[rl][col] = w_hh[(size_t)(gate * DD + wg * 4 + dl) * DD + col];
    }

    float c_reg = 0.f;
    const int r  = tid >> 5;     // row 0..15
    const int lp = tid & 31;     // slice lane (16 elems each)

    for (int s = 0; s < NV; ++s) {
        // stage h_{s-1}: ONE slot per thread (tid == d)
        if (s == 0) {
            h_s[tid < DD ? tid : 0] = 0.f;   // tid<512 == DD, all write
        } else {
            const u64* slot = slots + (size_t)(s - 1) * DD;
            u64 v = __hip_atomic_load(&slot[tid], __ATOMIC_RELAXED, __HIP_MEMORY_SCOPE_AGENT);
            while ((unsigned)(v & 0xffffffffull) != (unsigned)s) {
                v = __hip_atomic_load(&slot[tid], __ATOMIC_RELAXED, __HIP_MEMORY_SCOPE_AGENT);
            }
            union { unsigned u; float f; } cv; cv.u = (unsigned)(v >> 32);
            h_s[tid] = cv.f;
        }
        __syncthreads();   // also covers whh_s preload before first use

        // 16 row-dots, 32 lanes/row, 16 elems/lane (4 float4-pairs)
        float p = 0.f;
        const float4* wrow = (const float4*)&whh_s[r][0];
        const float4* hv4 = (const float4*)h_s;
#pragma unroll
        for (int q = 0; q < 4; ++q) {
            float4 wv = wrow[lp + 32 * q];
            float4 hv = hv4[lp + 32 * q];
            p += wv.x * hv.x + wv.y * hv.y + wv.z * hv.z + wv.w * hv.w;
        }
#pragma unroll
        for (int off = 16; off; off >>= 1) p += __shfl_down(p, off, 32);
        if (lp == 0) dot_s[r] = p;
        __syncthreads();

        if (tid < 4) {
            const int dg = wg * 4 + tid;
            const float* gxs = gx + s * (4 * DD);
            const float pi = gxs[0 * DD + dg] + dot_s[0  + tid];
            const float pf = gxs[1 * DD + dg] + dot_s[4  + tid];
            const float pg = gxs[2 * DD + dg] + dot_s[8  + tid];
            const float po = gxs[3 * DD + dg] + dot_s[12 + tid];
            const float si = 1.f / (1.f + expf(-pi));
            const float sf = 1.f / (1.f + expf(-pf));
            const float so = 1.f / (1.f + expf(-po));
            c_reg = sf * c_reg + si * tanhf(pg);
            const float hn = so * tanhf(c_reg);
            union { float f; unsigned u; } hv_; hv_.f = hn;
            const u64 pack = ((u64)hv_.u << 32) | (u64)(unsigned)(s + 1);
            __hip_atomic_store(&slots[(size_t)s * DD + dg], pack,
                               __ATOMIC_RELAXED, __HIP_MEMORY_SCOPE_AGENT);
        }
        // safe: h_s/dot_s only rewritten after the next step's syncs.
    }

    // classifier tail: out[n,cl] = h(step n) . w_cls[cl,:] + b_cls[cl]
    if (wg == 0) {
        for (int f = tid; f < NV * DD; f += 512) {
            const int ss = f >> 9, d = f & 511;
            u64 v = __hip_atomic_load(&slots[(size_t)ss * DD + d],
                                      __ATOMIC_RELAXED, __HIP_MEMORY_SCOPE_AGENT);
            while ((unsigned)(v & 0xffffffffull) != (unsigned)(ss + 1)) {
                v = __hip_atomic_load(&slots[(size_t)ss * DD + d],
                                      __ATOMIC_RELAXED, __HIP_MEMORY_SCOPE_AGENT);
            }
            union { unsigned u; float f; } cv; cv.u = (unsigned)(v >> 32);
            whh_s[ss][d] = cv.f;   // reuse rows 0..15 as h staging
        }
        __syncthreads();
        if (tid < NV * NCLS) {
            const int n = tid >> 3, cl = tid & 7;
            const float4* hv = (const float4*)&whh_s[n][0];
            const float4* wv = (const float4*)(w_cls + (size_t)cl * DD);
            float acc = b_cls[cl];
#pragma unroll 8
            for (int q = 0; q < DD / 4; ++q) {
                float4 a = hv[q], b = wv[q];
                acc += a.x * b.x + a.y * b.y + a.z * b.z + a.w * b.w;
            }
            out[tid] = acc;
        }
    }
}

extern "C" void kernel_launch(void* const* d_in, const int* in_sizes, int n_in,
                              void* d_out, int out_size, void* d_ws, size_t ws_size,
                              hipStream_t stream) {
    const float* base_out = (const float*)d_in[0];
    const float* dist     = (const float*)d_in[1];
    const float* w_a      = (const float*)d_in[2];
    const float* w_ih     = (const float*)d_in[3];
    const float* w_hh     = (const float*)d_in[4];
    const float* b_ih     = (const float*)d_in[5];
    const float* b_hh     = (const float*)d_in[6];
    const float* w_cls    = (const float*)d_in[7];
    const float* b_cls    = (const float*)d_in[8];
    float* out = (float*)d_out;

    float* ws = (float*)d_ws;
    float* pooled = ws + POOLED_F;
    float* gx     = ws + GX_F;
    u64*   slots  = (u64*)(ws + SLOT_F);
    float* part   = ws + PART_F;

    // 16-way split-K if the workspace allows (12.8 MB), else proven 4-way.
    const size_t need16 = ((size_t)PART_F + (size_t)16 * PART_STRIDE) * 4;
    const bool big = ws_size >= need16;

    if (big) k_gemm<16><<<dim3(16, 16), 256, 0, stream>>>(w_a, base_out, part);
    else     k_gemm<4> <<<dim3(4, 16),  256, 0, stream>>>(w_a, base_out, part);
    k_pool<<<dim3(16), 256, 0, stream>>>(part, dist, pooled, big ? 16 : 4);
    k_gx<<<dim3(128), 256, 0, stream>>>(pooled, w_ih, b_ih, b_hh, gx);
    k_lstm<<<dim3(128), 512, 0, stream>>>(w_hh, gx, w_cls, b_cls, slots, out);
}

// Round 5
// 273.243 us; speedup vs baseline: 1.5679x; 1.5679x over previous
//
#include <hip/hip_runtime.h>
#include <math.h>

// Problem constants (fixed by the reference)
#define MM 12       // M
#define KK 2        // K
#define DD 512      // D
#define CIN 4096    // C_IN
#define NCLS 8
#define NV 16       // N (videos) == LSTM step count
#define TT 32       // T
// Only LSTM batch row t=31 is ever consumed (rows independent; out uses hs[:, -1, :]).

typedef unsigned long long u64;
typedef __attribute__((ext_vector_type(8))) __bf16 bf16x8;
typedef __attribute__((ext_vector_type(4))) float f32x4;

// ws float offsets (total 3.18 MB <= 3.375 MB proven in R2)
#define PART_F   0            // 4*192*1024 floats; ALSO aliased by slots (8*16*512 u64 = 128K floats)
#define POOLED_F 786432       // 16*512
#define TAGA_F   794624       // 256 u32
#define TAGB_F   794880       // 256 u32
#define PART_KS_STRIDE (192 * 1024)

#define MFMA_BF16(A, B, C) __builtin_amdgcn_mfma_f32_16x16x32_bf16((A), (B), (C), 0, 0, 0)

__global__ __launch_bounds__(256, 1) void k_fused(
    const float* __restrict__ base_out, const float* __restrict__ dist,
    const float* __restrict__ w_a, const float* __restrict__ w_ih,
    const float* __restrict__ w_hh, const float* __restrict__ b_ih,
    const float* __restrict__ b_hh, const float* __restrict__ w_cls,
    const float* __restrict__ b_cls,
    float* __restrict__ part, float* __restrict__ pooled,
    unsigned* __restrict__ tagA, unsigned* __restrict__ tagB,
    u64* __restrict__ slots, float* __restrict__ out)
{
  const int wg = blockIdx.x;   // 0..255
  const int tid = threadIdx.x; // 0..255

  // Static LDS (~137 KB total; 1 WG/CU — static >64K proven OK in R3)
  __shared__ __align__(16) unsigned short Ah[16 * 40], Al[16 * 40];   // w_a tile hi/lo, pad-40 swizzle
  __shared__ __align__(16) unsigned short Bh[192 * 40], Bl[192 * 40]; // base_sel tile hi/lo
  __shared__ __align__(16) float whh_s[16][516];
  __shared__ __align__(16) float wih_s[16][516];
  __shared__ __align__(16) float pooled_s[16][520];  // also reused as h-history in classifier
  __shared__ float gx_s[16][20];                     // [n][rl], rl = gate*4 + dl
  __shared__ __align__(16) float h_s[DD];
  __shared__ float dot_s[16];
  __shared__ float Asum_s[KK * MM * MM];

  // =========================================================================
  // Phase A: GEMM part[ks][j][o] = w_a[o,:chunk] . base_sel[j,:chunk]
  // bf16x3 MFMA (hi/lo split), tile 16o x 192j per WG, KS=4, 32cc steps.
  // =========================================================================
  {
    const int ks = wg >> 6, ot = wg & 63;
    const int cc0 = ks * 1024;
    const int wave = tid >> 6, lane = tid & 63;
    const int jf0 = wave * 3;          // this wave's 3 j-fragments

    const int sq = tid & 7;            // cc float4 quad (0..7)
    const int sr = tid >> 3;           // staging row (0..31)
    unsigned boff[6];
#pragma unroll
    for (int rep = 0; rep < 6; ++rep) {
      const int j = sr + 32 * rep;     // 0..191
      const int n = j / 12, m = j - n * 12;
      boff[rep] = (unsigned)(((n * TT + 31) * MM + m) * CIN + cc0 + sq * 4);
    }
    const bool aact = tid < 128;       // A tile: 16 rows x 32cc = 128 float4
    unsigned aoff = aact ? (unsigned)((ot * 16 + (tid >> 3)) * CIN + cc0 + sq * 4) : 0u;

    f32x4 acc0 = {0.f, 0.f, 0.f, 0.f}, acc1 = acc0, acc2 = acc0;

    float4 pa, pb[6];
    if (aact) pa = *(const float4*)&w_a[aoff];
#pragma unroll
    for (int rep = 0; rep < 6; ++rep) pb[rep] = *(const float4*)&base_out[boff[rep]];

    for (int st = 0; st < 32; ++st) {
      __syncthreads();
      // convert f32 -> bf16 hi/lo (truncation; lo captures the residual) and stage
      if (aact) {
        const int idx = (tid >> 3) * 40 + sq * 4;
        unsigned ux = __float_as_uint(pa.x), uy = __float_as_uint(pa.y);
        unsigned uz = __float_as_uint(pa.z), uw = __float_as_uint(pa.w);
        *(uint2*)&Ah[idx] = make_uint2((ux >> 16) | (uy & 0xFFFF0000u),
                                       (uz >> 16) | (uw & 0xFFFF0000u));
        unsigned lx = __float_as_uint(pa.x - __uint_as_float(ux & 0xFFFF0000u));
        unsigned ly = __float_as_uint(pa.y - __uint_as_float(uy & 0xFFFF0000u));
        unsigned lz = __float_as_uint(pa.z - __uint_as_float(uz & 0xFFFF0000u));
        unsigned lw = __float_as_uint(pa.w - __uint_as_float(uw & 0xFFFF0000u));
        *(uint2*)&Al[idx] = make_uint2((lx >> 16) | (ly & 0xFFFF0000u),
                                       (lz >> 16) | (lw & 0xFFFF0000u));
      }
#pragma unroll
      for (int rep = 0; rep < 6; ++rep) {
        const int idx = (sr + 32 * rep) * 40 + sq * 4;
        unsigned ux = __float_as_uint(pb[rep].x), uy = __float_as_uint(pb[rep].y);
        unsigned uz = __float_as_uint(pb[rep].z), uw = __float_as_uint(pb[rep].w);
        *(uint2*)&Bh[idx] = make_uint2((ux >> 16) | (uy & 0xFFFF0000u),
                                       (uz >> 16) | (uw & 0xFFFF0000u));
        unsigned lx = __float_as_uint(pb[rep].x - __uint_as_float(ux & 0xFFFF0000u));
        unsigned ly = __float_as_uint(pb[rep].y - __uint_as_float(uy & 0xFFFF0000u));
        unsigned lz = __float_as_uint(pb[rep].z - __uint_as_float(uz & 0xFFFF0000u));
        unsigned lw = __float_as_uint(pb[rep].w - __uint_as_float(uw & 0xFFFF0000u));
        *(uint2*)&Bl[idx] = make_uint2((lx >> 16) | (ly & 0xFFFF0000u),
                                       (lz >> 16) | (lw & 0xFFFF0000u));
      }
      __syncthreads();
      if (st < 31) {  // prefetch next 32cc under compute
        aoff += 32;
        if (aact) pa = *(const float4*)&w_a[aoff];
#pragma unroll
        for (int rep = 0; rep < 6; ++rep) {
          boff[rep] += 32;
          pb[rep] = *(const float4*)&base_out[boff[rep]];
        }
      }
      // fragment loads + 3 accumulators x 3 bf16 passes
      const int koff = (lane >> 4) * 8;
      const int fra = (lane & 15) * 40 + koff;
      bf16x8 oh = *(const bf16x8*)&Ah[fra];
      bf16x8 ol = *(const bf16x8*)&Al[fra];
      {
        const int r0 = ((jf0 + 0) * 16 + (lane & 15)) * 40 + koff;
        bf16x8 jh = *(const bf16x8*)&Bh[r0], jl = *(const bf16x8*)&Bl[r0];
        acc0 = MFMA_BF16(jh, oh, acc0);
        acc0 = MFMA_BF16(jh, ol, acc0);
        acc0 = MFMA_BF16(jl, oh, acc0);
      }
      {
        const int r1 = ((jf0 + 1) * 16 + (lane & 15)) * 40 + koff;
        bf16x8 jh = *(const bf16x8*)&Bh[r1], jl = *(const bf16x8*)&Bl[r1];
        acc1 = MFMA_BF16(jh, oh, acc1);
        acc1 = MFMA_BF16(jh, ol, acc1);
        acc1 = MFMA_BF16(jl, oh, acc1);
      }
      {
        const int r2 = ((jf0 + 2) * 16 + (lane & 15)) * 40 + koff;
        bf16x8 jh = *(const bf16x8*)&Bh[r2], jl = *(const bf16x8*)&Bl[r2];
        acc2 = MFMA_BF16(jh, oh, acc2);
        acc2 = MFMA_BF16(jh, ol, acc2);
        acc2 = MFMA_BF16(jl, oh, acc2);
      }
    }
    // C/D layout: col(o) = lane&15, row(j) = (lane>>4)*4 + reg   [m89-verified]
    const int o = ot * 16 + (lane & 15);
    const int jr = (lane >> 4) * 4;
#pragma unroll
    for (int r = 0; r < 4; ++r) {
      part[((size_t)ks * 192 + (jf0 + 0) * 16 + jr + r) * 1024 + o] = acc0[r];
      part[((size_t)ks * 192 + (jf0 + 1) * 16 + jr + r) * 1024 + o] = acc1[r];
      part[((size_t)ks * 192 + (jf0 + 2) * 16 + jr + r) * 1024 + o] = acc2[r];
    }
    __syncthreads();   // drains vmcnt -> all part stores in L2 before release
    if (tid == 0)
      __hip_atomic_store(&tagA[wg], 1u, __ATOMIC_RELEASE, __HIP_MEMORY_SCOPE_AGENT);
  }

  // Overlap: preload LSTM weights into LDS while waiting on fence1
  if (wg < 128) {
    for (int f = tid; f < 16 * DD; f += 256) {
      const int rl = f >> 9, col = f & 511;
      const int row = (rl >> 2) * DD + wg * 4 + (rl & 3);   // gate*512 + dim
      whh_s[rl][col] = w_hh[(size_t)row * DD + col];
      wih_s[rl][col] = w_ih[(size_t)row * DD + col];
    }
  }

  // ---- fence 1: all GEMM tiles visible ----
  while (__hip_atomic_load(&tagA[tid], __ATOMIC_RELAXED, __HIP_MEMORY_SCOPE_AGENT) != 1u) {}
  __syncthreads();
  (void)__hip_atomic_load(&tagA[0], __ATOMIC_ACQUIRE, __HIP_MEMORY_SCOPE_AGENT);

  // =========================================================================
  // Phase B: pool — WG (n = wg>>4, c-block = (wg&15)*32)
  // =========================================================================
  {
    const int n = wg >> 4, cb = (wg & 15) * 32;
    const unsigned dbase = (unsigned)((n * TT + 31) * (3 * KK * MM * MM));
    for (int f = tid; f < KK * MM * MM; f += 256)
      Asum_s[f] = dist[dbase + f] + dist[dbase + KK * MM * MM + f]
                + dist[dbase + 2 * KK * MM * MM + f];
    __syncthreads();
    if (tid < 32) {
      const int c = cb + tid;
      float nd[KK][MM];
#pragma unroll
      for (int k = 0; k < KK; ++k)
#pragma unroll
        for (int v = 0; v < MM; ++v) {
          const size_t off = (size_t)(n * MM + v) * 1024 + k * DD + c;
          nd[k][v] = part[off] + part[off + PART_KS_STRIDE]
                   + part[off + 2 * PART_KS_STRIDE] + part[off + 3 * PART_KS_STRIDE];
        }
      float accm = 0.f;
#pragma unroll
      for (int w = 0; w < MM; ++w) {
        float sw = 0.f;
#pragma unroll
        for (int k = 0; k < KK; ++k)
#pragma unroll
          for (int v = 0; v < MM; ++v) sw += nd[k][v] * Asum_s[(k * MM + v) * MM + w];
        accm += fmaxf(sw, 0.f);
      }
      pooled[n * DD + c] = accm * (1.f / 12.f);
    }
    __syncthreads();
    if (tid == 0)
      __hip_atomic_store(&tagB[wg], 1u, __ATOMIC_RELEASE, __HIP_MEMORY_SCOPE_AGENT);
  }
  if (wg >= 128) return;   // only 128 WGs run the LSTM

  // ---- fence 2: pooled visible ----
  while (__hip_atomic_load(&tagB[tid], __ATOMIC_RELAXED, __HIP_MEMORY_SCOPE_AGENT) != 1u) {}
  __syncthreads();
  (void)__hip_atomic_load(&tagB[0], __ATOMIC_ACQUIRE, __HIP_MEMORY_SCOPE_AGENT);

  // =========================================================================
  // Phase C: gx in LDS — thread (rl = tid&15, n = tid>>4)
  // =========================================================================
  for (int f = tid; f < NV * DD; f += 256) pooled_s[f >> 9][f & 511] = pooled[f];
  __syncthreads();
  {
    const int rl = tid & 15, n = tid >> 4;
    const float4* wr = (const float4*)&wih_s[rl][0];
    const float4* pv = (const float4*)&pooled_s[n][0];
    float a = 0.f;
#pragma unroll 8
    for (int q = 0; q < DD / 4; ++q) {
      float4 x = wr[q], y = pv[q];
      a += x.x * y.x + x.y * y.y + x.z * y.z + x.w * y.w;
    }
    const int row = (rl >> 2) * DD + wg * 4 + (rl & 3);
    gx_s[n][rl] = a + b_ih[row] + b_hh[row];
  }
  __syncthreads();

  // =========================================================================
  // Phase D: LSTM, tagged dataflow with 8-replica publish (slots alias part;
  // part floats can't collide with tags 1..16 = denormal bit patterns).
  // =========================================================================
  {
    float c_reg = 0.f;
    const int r = tid >> 4;    // row 0..15
    const int lj = tid & 15;   // slice lane

    for (int s = 0; s < NV; ++s) {
      if (s == 0) {
        h_s[tid] = 0.f; h_s[tid + 256] = 0.f;
      } else {
        const u64* slot = slots + ((size_t)(wg & 7) * NV + (s - 1)) * DD;
        u64 v0 = __hip_atomic_load(&slot[tid], __ATOMIC_RELAXED, __HIP_MEMORY_SCOPE_AGENT);
        u64 v1 = __hip_atomic_load(&slot[tid + 256], __ATOMIC_RELAXED, __HIP_MEMORY_SCOPE_AGENT);
        while ((unsigned)v0 != (unsigned)s)
          v0 = __hip_atomic_load(&slot[tid], __ATOMIC_RELAXED, __HIP_MEMORY_SCOPE_AGENT);
        while ((unsigned)v1 != (unsigned)s)
          v1 = __hip_atomic_load(&slot[tid + 256], __ATOMIC_RELAXED, __HIP_MEMORY_SCOPE_AGENT);
        h_s[tid] = __uint_as_float((unsigned)(v0 >> 32));
        h_s[tid + 256] = __uint_as_float((unsigned)(v1 >> 32));
      }
      __syncthreads();

      float p = 0.f;
      const float4* wrow = (const float4*)&whh_s[r][0];
      const float4* hv4 = (const float4*)h_s;
#pragma unroll
      for (int q = 0; q < 8; ++q) {
        float4 wv = wrow[lj + 16 * q];
        float4 hv = hv4[lj + 16 * q];
        p += wv.x * hv.x + wv.y * hv.y + wv.z * hv.z + wv.w * hv.w;
      }
#pragma unroll
      for (int off = 8; off; off >>= 1) p += __shfl_down(p, off, 16);
      if (lj == 0) dot_s[r] = p;
      __syncthreads();

      u64 pack = 0;
      if (tid < 4) {
        const float pi = gx_s[s][tid]      + dot_s[tid];
        const float pf = gx_s[s][4 + tid]  + dot_s[4 + tid];
        const float pg = gx_s[s][8 + tid]  + dot_s[8 + tid];
        const float po = gx_s[s][12 + tid] + dot_s[12 + tid];
        const float si = 1.f / (1.f + expf(-pi));
        const float sf = 1.f / (1.f + expf(-pf));
        const float so = 1.f / (1.f + expf(-po));
        c_reg = sf * c_reg + si * tanhf(pg);
        const float hn = so * tanhf(c_reg);
        pack = ((u64)__float_as_uint(hn) << 32) | (u64)(unsigned)(s + 1);
      }
      if (tid < 32) {   // replicate to 8 buffers: one wave-store, 8 lines
        u64 pk = __shfl(pack, tid & 3, 64);
        const int rep = tid >> 2;
        __hip_atomic_store(&slots[((size_t)rep * NV + s) * DD + wg * 4 + (tid & 3)], pk,
                           __ATOMIC_RELAXED, __HIP_MEMORY_SCOPE_AGENT);
      }
      // safe: h_s/dot_s only rewritten after the next step's barriers
    }
  }

  // ---- classifier tail (WG 0): out[n,cl] = h(step n) . w_cls[cl] + b_cls ----
  if (wg == 0) {
    __syncthreads();
    for (int f = tid; f < NV * DD; f += 256) {
      const int ss = f >> 9, d = f & 511;
      u64 v = __hip_atomic_load(&slots[(size_t)ss * DD + d],
                                __ATOMIC_RELAXED, __HIP_MEMORY_SCOPE_AGENT);
      while ((unsigned)v != (unsigned)(ss + 1))
        v = __hip_atomic_load(&slots[(size_t)ss * DD + d],
                              __ATOMIC_RELAXED, __HIP_MEMORY_SCOPE_AGENT);
      pooled_s[ss][d] = __uint_as_float((unsigned)(v >> 32));
    }
    __syncthreads();
    if (tid < NV * NCLS) {
      const int n = tid >> 3, cl = tid & 7;
      const float4* hv = (const float4*)&pooled_s[n][0];
      const float4* wv = (const float4*)(w_cls + (size_t)cl * DD);
      float a = b_cls[cl];
#pragma unroll 8
      for (int q = 0; q < DD / 4; ++q) {
        float4 x = hv[q], y = wv[q];
        a += x.x * y.x + x.y * y.y + x.z * y.z + x.w * y.w;
      }
      out[tid] = a;
    }
  }
}

extern "C" void kernel_launch(void* const* d_in, const int* in_sizes, int n_in,
                              void* d_out, int out_size, void* d_ws, size_t ws_size,
                              hipStream_t stream) {
  const float* base_out = (const float*)d_in[0];
  const float* dist     = (const float*)d_in[1];
  const float* w_a      = (const float*)d_in[2];
  const float* w_ih     = (const float*)d_in[3];
  const float* w_hh     = (const float*)d_in[4];
  const float* b_ih     = (const float*)d_in[5];
  const float* b_hh     = (const float*)d_in[6];
  const float* w_cls    = (const float*)d_in[7];
  const float* b_cls    = (const float*)d_in[8];
  float* out = (float*)d_out;

  float* ws = (float*)d_ws;
  float* part   = ws + PART_F;
  float* pooled = ws + POOLED_F;
  unsigned* tagA = (unsigned*)(ws + TAGA_F);
  unsigned* tagB = (unsigned*)(ws + TAGB_F);
  u64* slots = (u64*)ws;   // aliases part (dead after phase B; tag check safe)

  // Tags/slots self-validate against the 0xAA re-poison; h_0 generated in-kernel.
  k_fused<<<dim3(256), 256, 0, stream>>>(base_out, dist, w_a, w_ih, w_hh,
                                         b_ih, b_hh, w_cls, b_cls,
                                         part, pooled, tagA, tagB, slots, out);
}